// Round 12
// baseline (318.247 us; speedup 1.0000x reference)
//
#include <hip/hip_runtime.h>
#include <stdint.h>

#pragma clang fp contract(off)

#define NPRI   136500
#define BATCH  8
#define NMS_K  5000
#define NKPAD  5120      // padded row count
#define TOPK   750
#define SORT_N 8192
#define HBINS  1024      // top16 float bits of s in (0.05,1] span [0x3D4C,0x3F80]
#define HOFF   0x3D40
#define MROW   80        // u64 words per mask row (79 used, padded)

// Exact threshold: RN(inter/uni) > 0.3f  <=>  inter > THR_D * uni (uni>0).
// 0.3f mantissa is even => RN(x) > 0.3f <=> x > 0.3f + ulp/2 = 0.3f + 2^-26.
// THR_D has 26 significand bits; uni has 24 => product exact in double.
#define THR_D (0.300000011920928955078125 + 1.490116119384765625e-8)

typedef unsigned long long u64;

__device__ __forceinline__ u64 shfl64(u64 v, int src) {
    int lo = __shfl((int)(unsigned)(v & 0xffffffffull), src);
    int hi = __shfl((int)(unsigned)(v >> 32), src);
    return ((u64)(unsigned)hi << 32) | (u64)(unsigned)lo;
}
__device__ __forceinline__ u64 shfl64_xor(u64 v, int m) {
    int lo = __shfl_xor((int)(unsigned)(v & 0xffffffffull), m);
    int hi = __shfl_xor((int)(unsigned)(v >> 32), m);
    return ((u64)(unsigned)hi << 32) | (u64)(unsigned)lo;
}

// -------- softmax score (cached to sraw) + LDS histogram of top-16 bits ---
__global__ __launch_bounds__(256) void score_hist_kernel(
        const float* __restrict__ conf, unsigned int* __restrict__ hist,
        float* __restrict__ sraw) {
    int b = blockIdx.y;
    __shared__ unsigned int h[HBINS];
    for (int i = threadIdx.x; i < HBINS; i += 256) h[i] = 0;
    __syncthreads();
    for (int p = blockIdx.x * 256 + threadIdx.x; p < NPRI; p += 64 * 256) {
        float2 c = ((const float2*)conf)[(size_t)b * NPRI + p];
        float m  = fmaxf(c.x, c.y);
        float e0 = expf(c.x - m), e1 = expf(c.y - m);
        float s  = e1 / (e0 + e1);
        sraw[(size_t)b * NPRI + p] = s;
        if (s > 0.05f) {
            int bin = (int)(__float_as_uint(s) >> 16) - HOFF;
            bin = min(max(bin, 0), HBINS - 1);
            atomicAdd(&h[bin], 1u);
        }
    }
    __syncthreads();
    for (int i = threadIdx.x; i < HBINS; i += 256) {
        unsigned int v = h[i];
        if (v) atomicAdd(&hist[b * HBINS + i], v);
    }
}

// -------- threshold bin t: largest t with count(bins >= t) >= NMS_K --------
__global__ __launch_bounds__(1024) void scan_kernel(
        const unsigned int* __restrict__ hist, int* __restrict__ tbin) {
    int b = blockIdx.x, t = threadIdx.x;
    __shared__ unsigned int v[HBINS];
    __shared__ int best;
    v[t] = hist[b * HBINS + t];
    if (t == 0) best = 0;
    __syncthreads();
    for (int o = 1; o < HBINS; o <<= 1) {   // reverse inclusive prefix sum
        unsigned int add = (t + o < HBINS) ? v[t + o] : 0u;
        __syncthreads();
        v[t] += add;
        __syncthreads();
    }
    if (v[t] >= (unsigned)NMS_K) atomicMax(&best, t);
    __syncthreads();
    if (t == 0) tbin[b] = best;
}

// -------- compact candidates (cached scores), one global atomic per block --
__global__ __launch_bounds__(256) void compact_kernel(
        const float* __restrict__ sraw, const int* __restrict__ tbin,
        u64* __restrict__ keys, unsigned int* __restrict__ cnt) {
    int p = blockIdx.x * 256 + threadIdx.x;
    int b = blockIdx.y;
    bool pass = false;
    unsigned int bits = 0;
    if (p < NPRI) {
        float s = sraw[(size_t)b * NPRI + p];
        if (s > 0.05f) {
            bits = __float_as_uint(s);
            int bin = (int)(bits >> 16) - HOFF;
            bin = min(max(bin, 0), HBINS - 1);
            pass = (bin >= tbin[b]);
        }
    }
    int w = threadIdx.x >> 6, lane = threadIdx.x & 63;
    u64 bal = __ballot(pass);
    int rank = (int)__popcll(bal & ((1ull << lane) - 1ull));
    __shared__ unsigned int woff[4];
    __shared__ unsigned int basesh;
    if (lane == 0) woff[w] = (unsigned)__popcll(bal);
    __syncthreads();
    if (threadIdx.x == 0) {
        unsigned t0 = woff[0], t1 = woff[1], t2 = woff[2], t3 = woff[3];
        unsigned tot = t0 + t1 + t2 + t3;
        basesh = tot ? atomicAdd(&cnt[b], tot) : 0u;
        woff[0] = 0; woff[1] = t0; woff[2] = t0 + t1; woff[3] = t0 + t1 + t2;
    }
    __syncthreads();
    if (pass) {
        unsigned pos = basesh + woff[w] + rank;
        if (pos < SORT_N)
            keys[(size_t)b * SORT_N + pos] =
                ((u64)bits << 32) | (u64)(~(unsigned int)p);
    }
}

// -------- bitonic stage 1: sort aligned 1024-chunks DESC (for merge) ------
__global__ __launch_bounds__(256) void sort1k_kernel(
        u64* __restrict__ keys, const unsigned int* __restrict__ cnt) {
    int b = blockIdx.y, c = blockIdx.x;     // chunk 0..7
    int tid = threadIdx.x;
    int n = min((int)cnt[b], SORT_N);
    int base = c * 1024;
    if (base >= n) {                        // all-zero chunk: skip the sort
        for (int i = tid; i < 1024; i += 256)
            keys[(size_t)b * SORT_N + base + i] = 0ull;
        return;
    }
    __shared__ u64 k[1024];                 // 8 KiB
    for (int i = tid; i < 1024; i += 256)
        k[i] = (base + i < n) ? keys[(size_t)b * SORT_N + base + i] : 0ull;
    __syncthreads();
    for (int kk = 2; kk <= 1024; kk <<= 1) {
        bool top = (kk == 1024);            // final stage: all descending
        for (int j = kk >> 1; j > 0; j >>= 1) {
            for (int i = tid; i < 1024; i += 256) {
                int ixj = i ^ j;
                if (ixj > i) {
                    u64 a = k[i], v = k[ixj];
                    bool desc = top || ((i & kk) == 0);
                    if (desc ? (a < v) : (a > v)) { k[i] = v; k[ixj] = a; }
                }
            }
            __syncthreads();
        }
    }
    for (int i = tid; i < 1024; i += 256)
        keys[(size_t)b * SORT_N + base + i] = k[i];
}

// -------- merge-path stage 0: (1024,1024)->2048 desc, 4 pairs/batch -------
__global__ __launch_bounds__(256) void merge0_kernel(
        const u64* __restrict__ keys, u64* __restrict__ keys2) {
    int b = blockIdx.y;
    int o = blockIdx.x * 256 + threadIdx.x;   // 0..8191
    int pair = o >> 11;
    int oo = o & 2047;
    const u64* A  = keys + (size_t)b * SORT_N + pair * 2048;
    const u64* Bp = A + 1024;
    int lo = max(0, oo - 1024), hi = min(oo, 1024);
    while (lo < hi) {
        int mid = (lo + hi + 1) >> 1;
        bool ok = (oo - mid >= 1024) || (A[mid - 1] >= Bp[oo - mid]);
        if (ok) lo = mid; else hi = mid - 1;
    }
    int i = lo, j = oo - lo;
    u64 v;
    if (j >= 1024) v = A[i];
    else if (i >= 1024) v = Bp[j];
    else v = (A[i] >= Bp[j]) ? A[i] : Bp[j];
    keys2[(size_t)b * SORT_N + pair * 2048 + oo] = v;
}

// -------- merge-path stage 1: (2048,2048)->4096 desc, two pairs/batch -----
__global__ __launch_bounds__(256) void merge1_kernel(
        const u64* __restrict__ keys2, u64* __restrict__ keys) {
    int b = blockIdx.y;
    int o = blockIdx.x * 256 + threadIdx.x;   // 0..8191
    int pair = o >> 12;
    int oo = o & 4095;
    const u64* A  = keys2 + (size_t)b * SORT_N + pair * 4096;
    const u64* Bp = A + 2048;
    int lo = max(0, oo - 2048), hi = min(oo, 2048);
    while (lo < hi) {
        int mid = (lo + hi + 1) >> 1;
        bool ok = (oo - mid >= 2048) || (A[mid - 1] >= Bp[oo - mid]);
        if (ok) lo = mid; else hi = mid - 1;
    }
    int i = lo, j = oo - lo;
    u64 v;
    if (j >= 2048) v = A[i];
    else if (i >= 2048) v = Bp[j];
    else v = (A[i] >= Bp[j]) ? A[i] : Bp[j];
    keys[(size_t)b * SORT_N + pair * 4096 + oo] = v;
}

// -------- merge-path stage 2 fused with decode: (4096,4096)->rows 0..4999 -
__global__ __launch_bounds__(256) void merge2_decode_kernel(
        const u64* __restrict__ keys,
        const float* __restrict__ loc, const float* __restrict__ priors,
        float* __restrict__ cscore, float* __restrict__ cbox,
        float* __restrict__ carea) {
    int b = blockIdx.y;
    int o = blockIdx.x * 256 + threadIdx.x;   // 0..5119
    const u64* A  = keys + (size_t)b * SORT_N;
    const u64* Bp = A + 4096;
    int lo = max(0, o - 4096), hi = min(o, 4096);
    while (lo < hi) {
        int mid = (lo + hi + 1) >> 1;
        bool ok = (o - mid >= 4096) || (A[mid - 1] >= Bp[o - mid]);
        if (ok) lo = mid; else hi = mid - 1;
    }
    int i = lo, j = o - lo;
    u64 key;
    if (j >= 4096) key = A[i];
    else if (i >= 4096) key = Bp[j];
    else key = (A[i] >= Bp[j]) ? A[i] : Bp[j];
    if (o >= NMS_K) return;                   // only rows 0..4999 consumed
    float sc; int idx;
    if (key != 0ull) {
        sc  = __uint_as_float((unsigned int)(key >> 32));
        idx = (int)(~(unsigned int)key);
    } else { sc = -1.0f; idx = 0; }
    cscore[b * NMS_K + o] = sc;
    float x1 = 0.f, y1 = 0.f, x2 = 0.f, y2 = 0.f, ar = 0.f;
    if (key != 0ull) {
        const float* l  = loc + ((size_t)b * NPRI + idx) * 4;
        const float* pr = priors + (size_t)idx * 4;
        float lx = l[0], ly = l[1], lw = l[2], lh = l[3];
        float pcx = pr[0], pcy = pr[1], pw = pr[2], ph = pr[3];
        float cx = pcx + (lx * 0.1f) * pw;
        float cy = pcy + (ly * 0.1f) * ph;
        float wd = pw * expf(lw * 0.2f);
        float ht = ph * expf(lh * 0.2f);
        x1 = cx - wd * 0.5f;  y1 = cy - ht * 0.5f;
        x2 = x1 + wd;         y2 = y1 + ht;
        ar = (x2 - x1) * (y2 - y1);
    }
    float* cb = cbox + ((size_t)b * NMS_K + o) * 4;
    cb[0] = x1; cb[1] = y1; cb[2] = x2; cb[3] = y2;
    carea[b * NMS_K + o] = ar;
}

// -------- row-major UPPER-TRIANGLE suppression mask: M[b][i][w] ----------
// 4 rows/thread: each column load + addressing amortized over 4 IoUs.
// Blocks: 512 rows x 4 words; compact triangle grid of 110 blocks/batch
// (count per wgq = wgq/2+1). Pure-f64 exact threshold test.
__global__ __launch_bounds__(128) void maskbuild_kernel(
        const float* __restrict__ cbox, const float* __restrict__ carea,
        u64* __restrict__ M) {
    int b   = blockIdx.y;
    int bid = blockIdx.x;               // 0..109
    int wgq = 0, cum = 0;
    while (cum + ((wgq >> 1) + 1) <= bid) { cum += (wgq >> 1) + 1; wgq++; }
    int rb = bid - cum;                 // 0..wgq/2
    int w0 = wgq * 4;
    int t  = threadIdx.x;
    bool clampcols = (wgq == 19);
    const float4* __restrict__ cb_col = (const float4*)cbox + (size_t)b * NMS_K;
    const float*  __restrict__ ca_col = carea + (size_t)b * NMS_K;
    int   irow[4];
    float rx1[4], ry1[4], rx2[4], ry2[4], rar[4];
#pragma unroll
    for (int r = 0; r < 4; r++) {
        irow[r] = rb * 512 + r * 128 + t;
        int ic = min(irow[r], NMS_K - 1);
        float4 c4 = cb_col[ic];
        rx1[r] = c4.x; ry1[r] = c4.y; rx2[r] = c4.z; ry2[r] = c4.w;
        rar[r] = ca_col[ic];
    }
    u64 res[4][4];                      // [word][row]
#pragma unroll
    for (int wi = 0; wi < 4; wi++) {
        int w = w0 + wi;
        int jbase = w << 6;
        u64 wd0 = 0, wd1 = 0, wd2 = 0, wd3 = 0;
#pragma unroll 4
        for (int jj = 0; jj < 64; jj++) {
            int jc = jbase + jj;
            if (clampcols) jc = min(jc, NMS_K - 1);   // masked by `valid`
            float4 c4 = cb_col[jc];
            float  aj = ca_col[jc];
            u64 bit = 1ull << jj;
#pragma unroll
            for (int r = 0; r < 4; r++) {
                float xx1 = fmaxf(c4.x, rx1[r]);
                float yy1 = fmaxf(c4.y, ry1[r]);
                float xx2 = fminf(c4.z, rx2[r]);
                float yy2 = fminf(c4.w, ry2[r]);
                float iw = fmaxf(xx2 - xx1, 0.0f);
                float ih = fmaxf(yy2 - yy1, 0.0f);
                float inter = iw * ih;
                float uni = (aj - inter) + rar[r];    // (area_j-inter)+area_i
                if ((double)inter > THR_D * (double)uni) {
                    if (r == 0) wd0 |= bit;
                    else if (r == 1) wd1 |= bit;
                    else if (r == 2) wd2 |= bit;
                    else wd3 |= bit;
                }
            }
        }
        u64 wda[4] = {wd0, wd1, wd2, wd3};
#pragma unroll
        for (int r = 0; r < 4; r++) {
            int ir = irow[r];
            u64 word = wda[r];
            if (ir >= jbase + 63) word = 0ull;        // no j>ir bits in word
            else if (ir >= jbase) word &= (~0ull << (ir - jbase + 1));
            res[wi][r] = word;
        }
    }
#pragma unroll
    for (int r = 0; r < 4; r++) {
        if (irow[r] < NMS_K) {
            u64* dst = M + ((size_t)b * NKPAD + irow[r]) * MROW + w0;
            ((ulonglong2*)dst)[0] = make_ulonglong2(res[0][r], res[1][r]);
            ((ulonglong2*)dst)[1] = make_ulonglong2(res[2][r], res[3][r]);
        }
    }
}

// -------- greedy scan: single barrier per word (unchanged from R10) -------
__global__ __launch_bounds__(1024) void maskscan_kernel(
        const float* __restrict__ cscore, const float* __restrict__ cbox,
        const unsigned int* __restrict__ cnt, const u64* __restrict__ M,
        float* __restrict__ out) {
    int b = blockIdx.x;
    int tid = threadIdx.x, lane = tid & 63, wv = tid >> 6;  // 16 waves
    int nv = min((int)cnt[b], NMS_K);
    const u64* MB = M + (size_t)b * NKPAD * MROW;
    float* outb = out + (size_t)b * 2 * TOPK * 5;
    __shared__ unsigned int supp32[2 * MROW];
    __shared__ u64 dbuf[2][64];
    __shared__ int plist[2][64];
    __shared__ short allp[TOPK];
    __shared__ int npick[2];
    __shared__ int emitted_sh;
    for (int i = tid; i < 2 * TOPK * 5; i += 1024) outb[i] = 0.f;  // zero out
    for (int i = tid; i < 2 * MROW; i += 1024) supp32[i] = 0u;
    if (tid == 0) { npick[0] = 0; npick[1] = 0; emitted_sh = 0; }
    if (wv == 1) dbuf[0][lane] = MB[(size_t)lane * MROW];  // diag(0)
    __syncthreads();
    int emitted = 0;
    int nwords = (nv + 63) >> 6;
    u64 colw_prev = 0ull;     // wave0: M[rows of word w-1][w], per lane
    u64 pickprev  = 0ull;     // wave0: pickmask of word w-1
    for (int w = 0; w < nwords; w++) {
        int par = w & 1;
        if (wv == 0) {
            u64 colw = MB[(size_t)(w * 64 + lane) * MROW + (w + 1)];
            u64 D = dbuf[par][lane];
            u64 sup = ((u64)supp32[2 * w + 1] << 32) | (u64)supp32[2 * w];
            u64 x = ((pickprev >> lane) & 1ull) ? colw_prev : 0ull;
#pragma unroll
            for (int m = 1; m < 64; m <<= 1) x |= shfl64_xor(x, m);
            sup |= x;
            int base = w * 64, rem = nv - base;
            u64 valid = (rem >= 64) ? ~0ull : ((1ull << rem) - 1ull);
            u64 alive = valid & ~sup;
            u64 nz = __ballot(D != 0ull);
            u64 pickmask = 0ull;
            while (alive) {
                u64 blockers = alive & nz;
                if (!blockers) { pickmask |= alive; break; }
                int nb = __builtin_ctzll(blockers);
                u64 mle = (nb >= 63) ? ~0ull : ((1ull << (nb + 1)) - 1ull);
                pickmask |= alive & mle;    // free run + the blocker itself
                u64 rw = shfl64(D, nb);     // blocker's in-word suppressions
                alive &= ~mle;
                alive &= ~rw;
            }
            int room = TOPK - emitted;
            int pc = __popcll(pickmask);
            while (pc > room) {             // keep lowest `room` picks
                pickmask &= ~(1ull << (63 - __builtin_clzll(pickmask)));
                pc--;
            }
            if (lane == 0) { npick[par] = pc; emitted_sh = emitted + pc; }
            if ((pickmask >> lane) & 1ull) {
                int rank = (int)__popcll(pickmask & ((1ull << lane) - 1ull));
                plist[par][rank] = base + lane;
                allp[emitted + rank] = (short)(base + lane);
            }
            pickprev = pickmask;
            colw_prev = colw;
        } else if (wv == 1) {
            if (w + 1 < nwords) {           // diag(w+1) -> other dbuf half
                u64 dpre = MB[(size_t)((w + 1) * 64 + lane) * MROW + (w + 1)];
                dbuf[(w + 1) & 1][lane] = dpre;
            }
        } else {
            // gather words >= w+1 of picks(w-1) -> OR into supp32
            int pn = npick[par ^ 1];
            for (int pk = wv - 2; pk < pn; pk += 14) {
                const u64* row = MB + (size_t)plist[par ^ 1][pk] * MROW;
                for (int wd = w + 1 + lane; wd < MROW; wd += 64) {
                    u64 v = row[wd];
                    if (v) {
                        atomicOr(&supp32[2 * wd],     (unsigned int)v);
                        atomicOr(&supp32[2 * wd + 1], (unsigned int)(v >> 32));
                    }
                }
            }
        }
        __syncthreads();                   // the single barrier per word
        emitted = emitted_sh;
        if (emitted >= TOPK) break;
    }
    // final emit: all picks at once, 16 waves
    for (int t = tid; t < emitted; t += 1024) {
        int p = allp[t];
        float sc  = cscore[b * NMS_K + p];
        float4 bx = ((const float4*)cbox)[(size_t)b * NMS_K + p];
        float* o = outb + (size_t)(TOPK + t) * 5;   // class 1 rows
        o[0] = sc; o[1] = bx.x; o[2] = bx.y; o[3] = bx.z; o[4] = bx.w;
    }
}

extern "C" void kernel_launch(void* const* d_in, const int* in_sizes, int n_in,
                              void* d_out, int out_size, void* d_ws, size_t ws_size,
                              hipStream_t stream) {
    const float* loc    = (const float*)d_in[0];
    const float* conf   = (const float*)d_in[1];
    const float* priors = (const float*)d_in[2];
    float* out = (float*)d_out;

    char* ws = (char*)d_ws;
    size_t off = 0;
    unsigned int* hist = (unsigned int*)(ws + off);   off += (size_t)BATCH * HBINS * 4; // 32 KiB
    unsigned int* cnt  = (unsigned int*)(ws + off);   off += 256;
    size_t zero_bytes = off;                          // hist + cnt only
    int* tbin = (int*)(ws + off);                     off += 256;
    u64* keys  = (u64*)(ws + off);                    off += (size_t)BATCH * SORT_N * 8;
    u64* keys2 = (u64*)(ws + off);                    off += (size_t)BATCH * SORT_N * 8;
    float* cscore = (float*)(ws + off);               off += (size_t)BATCH * NMS_K * 4;
    float* cbox   = (float*)(ws + off);               off += (size_t)BATCH * NMS_K * 16;
    float* carea  = (float*)(ws + off);               off += (size_t)BATCH * NMS_K * 4;
    u64* M = (u64*)(ws + off);                        off += (size_t)BATCH * NKPAD * MROW * 8; // 26.2 MB
    float* sraw = (float*)M;   // alias: sraw dead before maskbuild writes M

    hipMemsetAsync(d_ws, 0, zero_bytes, stream);

    score_hist_kernel<<<dim3(64, BATCH), 256, 0, stream>>>(conf, hist, sraw);
    scan_kernel<<<BATCH, HBINS, 0, stream>>>(hist, tbin);
    compact_kernel<<<dim3((NPRI + 255) / 256, BATCH), 256, 0, stream>>>(sraw, tbin, keys, cnt);
    sort1k_kernel<<<dim3(8, BATCH), 256, 0, stream>>>(keys, cnt);
    merge0_kernel<<<dim3(32, BATCH), 256, 0, stream>>>(keys, keys2);
    merge1_kernel<<<dim3(32, BATCH), 256, 0, stream>>>(keys2, keys);
    merge2_decode_kernel<<<dim3(20, BATCH), 256, 0, stream>>>(keys, loc, priors, cscore, cbox, carea);
    maskbuild_kernel<<<dim3(110, BATCH), 128, 0, stream>>>(cbox, carea, M);
    maskscan_kernel<<<BATCH, 1024, 0, stream>>>(cscore, cbox, cnt, M, out);
}

// Round 13
// 297.192 us; speedup vs baseline: 1.0708x; 1.0708x over previous
//
#include <hip/hip_runtime.h>
#include <stdint.h>

#pragma clang fp contract(off)

#define NPRI   136500
#define BATCH  8
#define NMS_K  5000
#define NKPAD  5120      // padded row count
#define TOPK   750
#define SORT_N 8192
#define HBINS  1024      // top16 float bits of s in (0.05,1] span [0x3D4C,0x3F80]
#define HOFF   0x3D40
#define MROW   80        // u64 words per mask row (79 used, padded)

// Exact threshold: RN(inter/uni) > 0.3f  <=>  inter > THR_D * uni (uni>0).
// 0.3f mantissa is even => RN(x) > 0.3f <=> x > 0.3f + ulp/2 = 0.3f + 2^-26.
// THR_D has 26 significand bits; uni has 24 => product exact in double.
#define THR_D (0.300000011920928955078125 + 1.490116119384765625e-8)

typedef unsigned long long u64;

__device__ __forceinline__ u64 shfl64(u64 v, int src) {
    int lo = __shfl((int)(unsigned)(v & 0xffffffffull), src);
    int hi = __shfl((int)(unsigned)(v >> 32), src);
    return ((u64)(unsigned)hi << 32) | (u64)(unsigned)lo;
}
__device__ __forceinline__ u64 shfl64_xor(u64 v, int m) {
    int lo = __shfl_xor((int)(unsigned)(v & 0xffffffffull), m);
    int hi = __shfl_xor((int)(unsigned)(v >> 32), m);
    return ((u64)(unsigned)hi << 32) | (u64)(unsigned)lo;
}

// -------- softmax score (cached to sraw) + LDS histogram of top-16 bits ---
__global__ __launch_bounds__(256) void score_hist_kernel(
        const float* __restrict__ conf, unsigned int* __restrict__ hist,
        float* __restrict__ sraw) {
    int b = blockIdx.y;
    __shared__ unsigned int h[HBINS];
    for (int i = threadIdx.x; i < HBINS; i += 256) h[i] = 0;
    __syncthreads();
    for (int p = blockIdx.x * 256 + threadIdx.x; p < NPRI; p += 64 * 256) {
        float2 c = ((const float2*)conf)[(size_t)b * NPRI + p];
        float m  = fmaxf(c.x, c.y);
        float e0 = expf(c.x - m), e1 = expf(c.y - m);
        float s  = e1 / (e0 + e1);
        sraw[(size_t)b * NPRI + p] = s;
        if (s > 0.05f) {
            int bin = (int)(__float_as_uint(s) >> 16) - HOFF;
            bin = min(max(bin, 0), HBINS - 1);
            atomicAdd(&h[bin], 1u);
        }
    }
    __syncthreads();
    for (int i = threadIdx.x; i < HBINS; i += 256) {
        unsigned int v = h[i];
        if (v) atomicAdd(&hist[b * HBINS + i], v);
    }
}

// -------- threshold bin t: largest t with count(bins >= t) >= NMS_K --------
__global__ __launch_bounds__(1024) void scan_kernel(
        const unsigned int* __restrict__ hist, int* __restrict__ tbin) {
    int b = blockIdx.x, t = threadIdx.x;
    __shared__ unsigned int v[HBINS];
    __shared__ int best;
    v[t] = hist[b * HBINS + t];
    if (t == 0) best = 0;
    __syncthreads();
    for (int o = 1; o < HBINS; o <<= 1) {   // reverse inclusive prefix sum
        unsigned int add = (t + o < HBINS) ? v[t + o] : 0u;
        __syncthreads();
        v[t] += add;
        __syncthreads();
    }
    if (v[t] >= (unsigned)NMS_K) atomicMax(&best, t);
    __syncthreads();
    if (t == 0) tbin[b] = best;
}

// -------- compact candidates (cached scores), one global atomic per block --
__global__ __launch_bounds__(256) void compact_kernel(
        const float* __restrict__ sraw, const int* __restrict__ tbin,
        u64* __restrict__ keys, unsigned int* __restrict__ cnt) {
    int p = blockIdx.x * 256 + threadIdx.x;
    int b = blockIdx.y;
    bool pass = false;
    unsigned int bits = 0;
    if (p < NPRI) {
        float s = sraw[(size_t)b * NPRI + p];
        if (s > 0.05f) {
            bits = __float_as_uint(s);
            int bin = (int)(bits >> 16) - HOFF;
            bin = min(max(bin, 0), HBINS - 1);
            pass = (bin >= tbin[b]);
        }
    }
    int w = threadIdx.x >> 6, lane = threadIdx.x & 63;
    u64 bal = __ballot(pass);
    int rank = (int)__popcll(bal & ((1ull << lane) - 1ull));
    __shared__ unsigned int woff[4];
    __shared__ unsigned int basesh;
    if (lane == 0) woff[w] = (unsigned)__popcll(bal);
    __syncthreads();
    if (threadIdx.x == 0) {
        unsigned t0 = woff[0], t1 = woff[1], t2 = woff[2], t3 = woff[3];
        unsigned tot = t0 + t1 + t2 + t3;
        basesh = tot ? atomicAdd(&cnt[b], tot) : 0u;
        woff[0] = 0; woff[1] = t0; woff[2] = t0 + t1; woff[3] = t0 + t1 + t2;
    }
    __syncthreads();
    if (pass) {
        unsigned pos = basesh + woff[w] + rank;
        if (pos < SORT_N)
            keys[(size_t)b * SORT_N + pos] =
                ((u64)bits << 32) | (u64)(~(unsigned int)p);
    }
}

// -------- bitonic stage 1: sort aligned 1024-chunks DESC (for merge) ------
__global__ __launch_bounds__(256) void sort1k_kernel(
        u64* __restrict__ keys, const unsigned int* __restrict__ cnt) {
    int b = blockIdx.y, c = blockIdx.x;     // chunk 0..7
    int tid = threadIdx.x;
    int n = min((int)cnt[b], SORT_N);
    int base = c * 1024;
    if (base >= n) {                        // all-zero chunk: skip the sort
        for (int i = tid; i < 1024; i += 256)
            keys[(size_t)b * SORT_N + base + i] = 0ull;
        return;
    }
    __shared__ u64 k[1024];                 // 8 KiB
    for (int i = tid; i < 1024; i += 256)
        k[i] = (base + i < n) ? keys[(size_t)b * SORT_N + base + i] : 0ull;
    __syncthreads();
    for (int kk = 2; kk <= 1024; kk <<= 1) {
        bool top = (kk == 1024);            // final stage: all descending
        for (int j = kk >> 1; j > 0; j >>= 1) {
            for (int i = tid; i < 1024; i += 256) {
                int ixj = i ^ j;
                if (ixj > i) {
                    u64 a = k[i], v = k[ixj];
                    bool desc = top || ((i & kk) == 0);
                    if (desc ? (a < v) : (a > v)) { k[i] = v; k[ixj] = a; }
                }
            }
            __syncthreads();
        }
    }
    for (int i = tid; i < 1024; i += 256)
        keys[(size_t)b * SORT_N + base + i] = k[i];
}

// -------- merge-path stage 0: (1024,1024)->2048 desc, 4 pairs/batch -------
__global__ __launch_bounds__(256) void merge0_kernel(
        const u64* __restrict__ keys, u64* __restrict__ keys2) {
    int b = blockIdx.y;
    int o = blockIdx.x * 256 + threadIdx.x;   // 0..8191
    int pair = o >> 11;
    int oo = o & 2047;
    const u64* A  = keys + (size_t)b * SORT_N + pair * 2048;
    const u64* Bp = A + 1024;
    int lo = max(0, oo - 1024), hi = min(oo, 1024);
    while (lo < hi) {
        int mid = (lo + hi + 1) >> 1;
        bool ok = (oo - mid >= 1024) || (A[mid - 1] >= Bp[oo - mid]);
        if (ok) lo = mid; else hi = mid - 1;
    }
    int i = lo, j = oo - lo;
    u64 v;
    if (j >= 1024) v = A[i];
    else if (i >= 1024) v = Bp[j];
    else v = (A[i] >= Bp[j]) ? A[i] : Bp[j];
    keys2[(size_t)b * SORT_N + pair * 2048 + oo] = v;
}

// -------- merge-path stage 1: (2048,2048)->4096 desc, two pairs/batch -----
__global__ __launch_bounds__(256) void merge1_kernel(
        const u64* __restrict__ keys2, u64* __restrict__ keys) {
    int b = blockIdx.y;
    int o = blockIdx.x * 256 + threadIdx.x;   // 0..8191
    int pair = o >> 12;
    int oo = o & 4095;
    const u64* A  = keys2 + (size_t)b * SORT_N + pair * 4096;
    const u64* Bp = A + 2048;
    int lo = max(0, oo - 2048), hi = min(oo, 2048);
    while (lo < hi) {
        int mid = (lo + hi + 1) >> 1;
        bool ok = (oo - mid >= 2048) || (A[mid - 1] >= Bp[oo - mid]);
        if (ok) lo = mid; else hi = mid - 1;
    }
    int i = lo, j = oo - lo;
    u64 v;
    if (j >= 2048) v = A[i];
    else if (i >= 2048) v = Bp[j];
    else v = (A[i] >= Bp[j]) ? A[i] : Bp[j];
    keys[(size_t)b * SORT_N + pair * 4096 + oo] = v;
}

// -------- merge-path stage 2 fused with decode: (4096,4096)->rows 0..4999 -
__global__ __launch_bounds__(256) void merge2_decode_kernel(
        const u64* __restrict__ keys,
        const float* __restrict__ loc, const float* __restrict__ priors,
        float* __restrict__ cscore, float* __restrict__ cbox,
        float* __restrict__ carea) {
    int b = blockIdx.y;
    int o = blockIdx.x * 256 + threadIdx.x;   // 0..5119
    const u64* A  = keys + (size_t)b * SORT_N;
    const u64* Bp = A + 4096;
    int lo = max(0, o - 4096), hi = min(o, 4096);
    while (lo < hi) {
        int mid = (lo + hi + 1) >> 1;
        bool ok = (o - mid >= 4096) || (A[mid - 1] >= Bp[o - mid]);
        if (ok) lo = mid; else hi = mid - 1;
    }
    int i = lo, j = o - lo;
    u64 key;
    if (j >= 4096) key = A[i];
    else if (i >= 4096) key = Bp[j];
    else key = (A[i] >= Bp[j]) ? A[i] : Bp[j];
    if (o >= NMS_K) return;                   // only rows 0..4999 consumed
    float sc; int idx;
    if (key != 0ull) {
        sc  = __uint_as_float((unsigned int)(key >> 32));
        idx = (int)(~(unsigned int)key);
    } else { sc = -1.0f; idx = 0; }
    cscore[b * NMS_K + o] = sc;
    float x1 = 0.f, y1 = 0.f, x2 = 0.f, y2 = 0.f, ar = 0.f;
    if (key != 0ull) {
        const float* l  = loc + ((size_t)b * NPRI + idx) * 4;
        const float* pr = priors + (size_t)idx * 4;
        float lx = l[0], ly = l[1], lw = l[2], lh = l[3];
        float pcx = pr[0], pcy = pr[1], pw = pr[2], ph = pr[3];
        float cx = pcx + (lx * 0.1f) * pw;
        float cy = pcy + (ly * 0.1f) * ph;
        float wd = pw * expf(lw * 0.2f);
        float ht = ph * expf(lh * 0.2f);
        x1 = cx - wd * 0.5f;  y1 = cy - ht * 0.5f;
        x2 = x1 + wd;         y2 = y1 + ht;
        ar = (x2 - x1) * (y2 - y1);
    }
    float* cb = cbox + ((size_t)b * NMS_K + o) * 4;
    cb[0] = x1; cb[1] = y1; cb[2] = x2; cb[3] = y2;
    carea[b * NMS_K + o] = ar;
}

// -------- row-major UPPER-TRIANGLE suppression mask: M[b][i][w] ----------
// R9/R10 proven config: 1 row/thread, 4 words, 420-block compact triangle
// grid (measured 77 us, VALUBusy 81%). Pure-f64 exact threshold test.
__global__ __launch_bounds__(128) void maskbuild_kernel(
        const float* __restrict__ cbox, const float* __restrict__ carea,
        u64* __restrict__ M) {
    int b   = blockIdx.y;
    int bid = blockIdx.x;               // 0..419
    int wgq, rb;
    if (bid >= 380) { wgq = 19; rb = bid - 380; }
    else {
        int w = (int)((sqrtf((float)(4 * bid + 5)) - 1.0f) * 0.5f);
        while (w * (w + 1) > bid) w--;
        while ((w + 1) * (w + 2) <= bid) w++;
        wgq = w; rb = bid - w * (w + 1);    // rb <= 2*wgq+1 by construction
    }
    int i = rb * 128 + threadIdx.x;
    int w0 = wgq * 4;
    if (i >= NMS_K) return;
    const float4* __restrict__ cb_col = (const float4*)cbox + (size_t)b * NMS_K;
    const float*  __restrict__ ca_col = carea + (size_t)b * NMS_K;
    float4 rbx = cb_col[i];
    float  ra  = ca_col[i];
    u64 res[4];
    if (wgq < 19) {                     // clamp-free fast path
#pragma unroll
        for (int wi = 0; wi < 4; wi++) {
            int w = w0 + wi;
            u64 word = 0ull;
            if (i < 64 * w + 64) {
                int jbase = w << 6;
#pragma unroll 8
                for (int jj = 0; jj < 64; jj++) {
                    int jc = jbase + jj;
                    float4 c4 = cb_col[jc];
                    float  aj = ca_col[jc];
                    float xx1 = fmaxf(c4.x, rbx.x);
                    float yy1 = fmaxf(c4.y, rbx.y);
                    float xx2 = fminf(c4.z, rbx.z);
                    float yy2 = fminf(c4.w, rbx.w);
                    float iw = fmaxf(xx2 - xx1, 0.0f);
                    float ih = fmaxf(yy2 - yy1, 0.0f);
                    float inter = iw * ih;
                    float uni = (aj - inter) + ra;    // (area_j-inter)+area_i
                    if ((double)inter > THR_D * (double)uni)
                        word |= (1ull << jj);
                }
                if (i >= 64 * w) {
                    int sh = i - 64 * w;
                    word &= (sh == 63) ? 0ull : (~0ull << (sh + 1));
                }
            }
            res[wi] = word;
        }
    } else {                            // last group: clamp columns
#pragma unroll
        for (int wi = 0; wi < 4; wi++) {
            int w = w0 + wi;
            u64 word = 0ull;
            if (i < 64 * w + 64) {
                int jbase = w << 6;
#pragma unroll 8
                for (int jj = 0; jj < 64; jj++) {
                    int jc = jbase + jj;
                    if (jc > NMS_K - 1) jc = NMS_K - 1;  // masked by `valid`
                    float4 c4 = cb_col[jc];
                    float  aj = ca_col[jc];
                    float xx1 = fmaxf(c4.x, rbx.x);
                    float yy1 = fmaxf(c4.y, rbx.y);
                    float xx2 = fminf(c4.z, rbx.z);
                    float yy2 = fminf(c4.w, rbx.w);
                    float iw = fmaxf(xx2 - xx1, 0.0f);
                    float ih = fmaxf(yy2 - yy1, 0.0f);
                    float inter = iw * ih;
                    float uni = (aj - inter) + ra;
                    if ((double)inter > THR_D * (double)uni)
                        word |= (1ull << jj);
                }
                if (i >= 64 * w) {
                    int sh = i - 64 * w;
                    word &= (sh == 63) ? 0ull : (~0ull << (sh + 1));
                }
            }
            res[wi] = word;
        }
    }
    u64* dst = M + ((size_t)b * NKPAD + i) * MROW + w0;   // 32 B contiguous
    ((ulonglong2*)dst)[0] = make_ulonglong2(res[0], res[1]);
    ((ulonglong2*)dst)[1] = make_ulonglong2(res[2], res[3]);
}

// -------- greedy scan: single barrier per word (R10, verified) ------------
__global__ __launch_bounds__(1024) void maskscan_kernel(
        const float* __restrict__ cscore, const float* __restrict__ cbox,
        const unsigned int* __restrict__ cnt, const u64* __restrict__ M,
        float* __restrict__ out) {
    int b = blockIdx.x;
    int tid = threadIdx.x, lane = tid & 63, wv = tid >> 6;  // 16 waves
    int nv = min((int)cnt[b], NMS_K);
    const u64* MB = M + (size_t)b * NKPAD * MROW;
    float* outb = out + (size_t)b * 2 * TOPK * 5;
    __shared__ unsigned int supp32[2 * MROW];
    __shared__ u64 dbuf[2][64];
    __shared__ int plist[2][64];
    __shared__ short allp[TOPK];
    __shared__ int npick[2];
    __shared__ int emitted_sh;
    for (int i = tid; i < 2 * TOPK * 5; i += 1024) outb[i] = 0.f;  // zero out
    for (int i = tid; i < 2 * MROW; i += 1024) supp32[i] = 0u;
    if (tid == 0) { npick[0] = 0; npick[1] = 0; emitted_sh = 0; }
    if (wv == 1) dbuf[0][lane] = MB[(size_t)lane * MROW];  // diag(0)
    __syncthreads();
    int emitted = 0;
    int nwords = (nv + 63) >> 6;
    u64 colw_prev = 0ull;     // wave0: M[rows of word w-1][w], per lane
    u64 pickprev  = 0ull;     // wave0: pickmask of word w-1
    for (int w = 0; w < nwords; w++) {
        int par = w & 1;
        if (wv == 0) {
            u64 colw = MB[(size_t)(w * 64 + lane) * MROW + (w + 1)];
            u64 D = dbuf[par][lane];
            u64 sup = ((u64)supp32[2 * w + 1] << 32) | (u64)supp32[2 * w];
            u64 x = ((pickprev >> lane) & 1ull) ? colw_prev : 0ull;
#pragma unroll
            for (int m = 1; m < 64; m <<= 1) x |= shfl64_xor(x, m);
            sup |= x;
            int base = w * 64, rem = nv - base;
            u64 valid = (rem >= 64) ? ~0ull : ((1ull << rem) - 1ull);
            u64 alive = valid & ~sup;
            u64 nz = __ballot(D != 0ull);
            u64 pickmask = 0ull;
            while (alive) {
                u64 blockers = alive & nz;
                if (!blockers) { pickmask |= alive; break; }
                int nb = __builtin_ctzll(blockers);
                u64 mle = (nb >= 63) ? ~0ull : ((1ull << (nb + 1)) - 1ull);
                pickmask |= alive & mle;    // free run + the blocker itself
                u64 rw = shfl64(D, nb);     // blocker's in-word suppressions
                alive &= ~mle;
                alive &= ~rw;
            }
            int room = TOPK - emitted;
            int pc = __popcll(pickmask);
            while (pc > room) {             // keep lowest `room` picks
                pickmask &= ~(1ull << (63 - __builtin_clzll(pickmask)));
                pc--;
            }
            if (lane == 0) { npick[par] = pc; emitted_sh = emitted + pc; }
            if ((pickmask >> lane) & 1ull) {
                int rank = (int)__popcll(pickmask & ((1ull << lane) - 1ull));
                plist[par][rank] = base + lane;
                allp[emitted + rank] = (short)(base + lane);
            }
            pickprev = pickmask;
            colw_prev = colw;
        } else if (wv == 1) {
            if (w + 1 < nwords) {           // diag(w+1) -> other dbuf half
                u64 dpre = MB[(size_t)((w + 1) * 64 + lane) * MROW + (w + 1)];
                dbuf[(w + 1) & 1][lane] = dpre;
            }
        } else {
            // gather words >= w+1 of picks(w-1) -> OR into supp32
            int pn = npick[par ^ 1];
            for (int pk = wv - 2; pk < pn; pk += 14) {
                const u64* row = MB + (size_t)plist[par ^ 1][pk] * MROW;
                for (int wd = w + 1 + lane; wd < MROW; wd += 64) {
                    u64 v = row[wd];
                    if (v) {
                        atomicOr(&supp32[2 * wd],     (unsigned int)v);
                        atomicOr(&supp32[2 * wd + 1], (unsigned int)(v >> 32));
                    }
                }
            }
        }
        __syncthreads();                   // the single barrier per word
        emitted = emitted_sh;
        if (emitted >= TOPK) break;
    }
    // final emit: all picks at once, 16 waves
    for (int t = tid; t < emitted; t += 1024) {
        int p = allp[t];
        float sc  = cscore[b * NMS_K + p];
        float4 bx = ((const float4*)cbox)[(size_t)b * NMS_K + p];
        float* o = outb + (size_t)(TOPK + t) * 5;   // class 1 rows
        o[0] = sc; o[1] = bx.x; o[2] = bx.y; o[3] = bx.z; o[4] = bx.w;
    }
}

extern "C" void kernel_launch(void* const* d_in, const int* in_sizes, int n_in,
                              void* d_out, int out_size, void* d_ws, size_t ws_size,
                              hipStream_t stream) {
    const float* loc    = (const float*)d_in[0];
    const float* conf   = (const float*)d_in[1];
    const float* priors = (const float*)d_in[2];
    float* out = (float*)d_out;

    char* ws = (char*)d_ws;
    size_t off = 0;
    unsigned int* hist = (unsigned int*)(ws + off);   off += (size_t)BATCH * HBINS * 4; // 32 KiB
    unsigned int* cnt  = (unsigned int*)(ws + off);   off += 256;
    size_t zero_bytes = off;                          // hist + cnt only
    int* tbin = (int*)(ws + off);                     off += 256;
    u64* keys  = (u64*)(ws + off);                    off += (size_t)BATCH * SORT_N * 8;
    u64* keys2 = (u64*)(ws + off);                    off += (size_t)BATCH * SORT_N * 8;
    float* cscore = (float*)(ws + off);               off += (size_t)BATCH * NMS_K * 4;
    float* cbox   = (float*)(ws + off);               off += (size_t)BATCH * NMS_K * 16;
    float* carea  = (float*)(ws + off);               off += (size_t)BATCH * NMS_K * 4;
    u64* M = (u64*)(ws + off);                        off += (size_t)BATCH * NKPAD * MROW * 8; // 26.2 MB
    float* sraw = (float*)M;   // alias: sraw dead before maskbuild writes M

    hipMemsetAsync(d_ws, 0, zero_bytes, stream);

    score_hist_kernel<<<dim3(64, BATCH), 256, 0, stream>>>(conf, hist, sraw);
    scan_kernel<<<BATCH, HBINS, 0, stream>>>(hist, tbin);
    compact_kernel<<<dim3((NPRI + 255) / 256, BATCH), 256, 0, stream>>>(sraw, tbin, keys, cnt);
    sort1k_kernel<<<dim3(8, BATCH), 256, 0, stream>>>(keys, cnt);
    merge0_kernel<<<dim3(32, BATCH), 256, 0, stream>>>(keys, keys2);
    merge1_kernel<<<dim3(32, BATCH), 256, 0, stream>>>(keys2, keys);
    merge2_decode_kernel<<<dim3(20, BATCH), 256, 0, stream>>>(keys, loc, priors, cscore, cbox, carea);
    maskbuild_kernel<<<dim3(420, BATCH), 128, 0, stream>>>(cbox, carea, M);
    maskscan_kernel<<<BATCH, 1024, 0, stream>>>(cscore, cbox, cnt, M, out);
}